// Round 7
// baseline (2454.039 us; speedup 1.0000x reference)
//
#include <hip/hip_runtime.h>
#include <stdint.h>

// Problem constants (fixed by reference): B=32, T=512, d=1024, Kcb=256
#define NB    32
#define NT    512
#define ND    1024
#define NG    3072      // 3*d
#define NROW  16384     // B*T
#define KCB   256
#define GRU_BLOCKS 128  // 2 independent batch-groups x 64 col-blocks (16 cols each)

typedef float  f32x4 __attribute__((ext_vector_type(4)));
typedef short  s16x8 __attribute__((ext_vector_type(8)));
typedef int    i32x4 __attribute__((ext_vector_type(4)));

// ---------------- bf16 helpers (hi/lo split precision) ----------------
__device__ __forceinline__ unsigned short f32_to_bf16(float x) {
    union { float f; unsigned int u; } v; v.f = x;
    unsigned int u = v.u;
    return (unsigned short)((u + 0x7FFFu + ((u >> 16) & 1u)) >> 16);
}
__device__ __forceinline__ float bf16_to_f32(unsigned short h) {
    union { float f; unsigned int u; } v; v.u = ((unsigned int)h) << 16; return v.f;
}

// LLC-coherent (L1/L2-bypassing) accesses — cross-XCD fresh without fences.
__device__ __forceinline__ i32x4 llc_load16i(const int* p) {
    i32x4 r;
    asm volatile("global_load_dwordx4 %0, %1, off sc0 sc1" : "=v"(r) : "v"(p) : "memory");
    return r;
}
__device__ __forceinline__ void llc_store4(int* p, int v) {
    asm volatile("global_store_dword %0, %1, off sc0 sc1" :: "v"(p), "v"(v) : "memory");
}

// ---------------- fused prep: hi/lo splits of W_hh, W_proj, cb + ||c||^2 ----------------
__device__ __forceinline__ void split8(const float* __restrict__ X,
                                       unsigned short* __restrict__ Hi,
                                       unsigned short* __restrict__ Lo, int blk) {
    long i8 = ((long)blk * 256 + threadIdx.x) * 8;
    float4 a = *(const float4*)(X + i8);
    float4 b = *(const float4*)(X + i8 + 4);
    float xs[8] = {a.x, a.y, a.z, a.w, b.x, b.y, b.z, b.w};
    s16x8 hi, lo;
    #pragma unroll
    for (int j = 0; j < 8; ++j) {
        unsigned short h = f32_to_bf16(xs[j]);
        hi[j] = (short)h;
        lo[j] = (short)f32_to_bf16(xs[j] - bf16_to_f32(h));
    }
    *(s16x8*)(Hi + i8) = hi;
    *(s16x8*)(Lo + i8) = lo;
}

__global__ __launch_bounds__(256) void prep_fused(
    const float* __restrict__ Whh, const float* __restrict__ Wproj,
    const float* __restrict__ cb,
    unsigned short* __restrict__ Whi, unsigned short* __restrict__ Wlo,
    unsigned short* __restrict__ Phi, unsigned short* __restrict__ Plo,
    unsigned short* __restrict__ cbHi, unsigned short* __restrict__ cbLo,
    float* __restrict__ ccg)
{
    int bid = blockIdx.x;
    if (bid < 1536)      split8(Whh,   Whi,  Wlo,  bid);          // 3072x1024
    else if (bid < 2048) split8(Wproj, Phi,  Plo,  bid - 1536);   // 1024x1024
    else if (bid < 2176) split8(cb,    cbHi, cbLo, bid - 2048);   // 256x1024
    else {
        // ||c||^2 in fp64, one block
        int c = threadIdx.x;
        const float4* row = (const float4*)(cb + (long)c * ND);
        double s = 0.0;
        for (int i = 0; i < 256; ++i) {
            float4 v = row[i];
            s += (double)v.x * (double)v.x + (double)v.y * (double)v.y
               + (double)v.z * (double)v.z + (double)v.w * (double)v.w;
        }
        ccg[c] = (float)s;
    }
}

// ---------------- MFMA quantize: in-register feat hi/lo split ----------------
__global__ __launch_bounds__(256, 1) void quantize_mfma(
    const float* __restrict__ feat, const float* __restrict__ cb,
    const unsigned short* __restrict__ cHi, const unsigned short* __restrict__ cLo,
    const float* __restrict__ ccg,
    float* __restrict__ out_q, float* __restrict__ out_idx,
    int* __restrict__ idxi, float* __restrict__ acc)
{
    __shared__ unsigned short cbsH[256][64];   // 32 KB, k XOR-swizzled
    __shared__ unsigned short cbsL[256][64];   // 32 KB
    __shared__ float ccs[256];
    __shared__ int   widx[64];
    __shared__ float sp[4];

    int tid  = threadIdx.x;
    int lane = tid & 63;
    int w    = tid >> 6;
    int r0   = blockIdx.x * 64;
    int tm   = lane & 15;
    int q    = lane >> 4;

    ccs[tid] = ccg[tid];

    f32x4 dacc[16];
    #pragma unroll
    for (int n = 0; n < 16; ++n) dacc[n] = (f32x4){0.f, 0.f, 0.f, 0.f};

    const long arow = (long)(r0 + w * 16 + tm) * ND;

    for (int kc = 0; kc < 16; ++kc) {
        int k0 = kc * 64;
        #pragma unroll
        for (int it = 0; it < 8; ++it) {
            int u    = it * 256 + tid;
            int code = u >> 3;
            int j8   = u & 7;
            int ksw  = (j8 * 8) ^ ((code & 7) << 3);
            *(s16x8*)&cbsH[code][ksw] = *(const s16x8*)(cHi + (long)code * ND + k0 + j8 * 8);
            *(s16x8*)&cbsL[code][ksw] = *(const s16x8*)(cLo + (long)code * ND + k0 + j8 * 8);
        }
        float4 a0 = *(const float4*)(feat + arow + k0 + q * 8);
        float4 a1 = *(const float4*)(feat + arow + k0 + q * 8 + 4);
        float4 a2 = *(const float4*)(feat + arow + k0 + 32 + q * 8);
        float4 a3 = *(const float4*)(feat + arow + k0 + 32 + q * 8 + 4);
        s16x8 ah0, al0, ah1, al1;
        {
            float xs[8] = {a0.x, a0.y, a0.z, a0.w, a1.x, a1.y, a1.z, a1.w};
            #pragma unroll
            for (int j = 0; j < 8; ++j) {
                unsigned short h = f32_to_bf16(xs[j]);
                ah0[j] = (short)h;
                al0[j] = (short)f32_to_bf16(xs[j] - bf16_to_f32(h));
            }
            float ys[8] = {a2.x, a2.y, a2.z, a2.w, a3.x, a3.y, a3.z, a3.w};
            #pragma unroll
            for (int j = 0; j < 8; ++j) {
                unsigned short h = f32_to_bf16(ys[j]);
                ah1[j] = (short)h;
                al1[j] = (short)f32_to_bf16(ys[j] - bf16_to_f32(h));
            }
        }
        __syncthreads();
        int ksw0 = (q * 8) ^ ((tm & 7) << 3);
        int ksw1 = (32 + q * 8) ^ ((tm & 7) << 3);
        #pragma unroll
        for (int n = 0; n < 16; ++n) {
            s16x8 bh0 = *(const s16x8*)&cbsH[n * 16 + tm][ksw0];
            s16x8 bh1 = *(const s16x8*)&cbsH[n * 16 + tm][ksw1];
            s16x8 bl0 = *(const s16x8*)&cbsL[n * 16 + tm][ksw0];
            s16x8 bl1 = *(const s16x8*)&cbsL[n * 16 + tm][ksw1];
            dacc[n] = __builtin_amdgcn_mfma_f32_16x16x32_bf16(ah0, bh0, dacc[n], 0, 0, 0);
            dacc[n] = __builtin_amdgcn_mfma_f32_16x16x32_bf16(al0, bh0, dacc[n], 0, 0, 0);
            dacc[n] = __builtin_amdgcn_mfma_f32_16x16x32_bf16(ah0, bl0, dacc[n], 0, 0, 0);
            dacc[n] = __builtin_amdgcn_mfma_f32_16x16x32_bf16(ah1, bh1, dacc[n], 0, 0, 0);
            dacc[n] = __builtin_amdgcn_mfma_f32_16x16x32_bf16(al1, bh1, dacc[n], 0, 0, 0);
            dacc[n] = __builtin_amdgcn_mfma_f32_16x16x32_bf16(ah1, bl1, dacc[n], 0, 0, 0);
        }
        __syncthreads();
    }

    float best[4] = {3.4e38f, 3.4e38f, 3.4e38f, 3.4e38f};
    int   bidx[4] = {0, 0, 0, 0};
    #pragma unroll
    for (int n = 0; n < 16; ++n) {
        int code = n * 16 + tm;
        float ccv = ccs[code];
        #pragma unroll
        for (int r = 0; r < 4; ++r) {
            float d = ccv - 2.f * dacc[n][r];
            if (d < best[r]) { best[r] = d; bidx[r] = code; }
        }
    }
    #pragma unroll
    for (int r = 0; r < 4; ++r) {
        #pragma unroll
        for (int m = 1; m < 16; m <<= 1) {
            float ob = __shfl_xor(best[r], m, 64);
            int   oi = __shfl_xor(bidx[r], m, 64);
            if (ob < best[r] || (ob == best[r] && oi < bidx[r])) { best[r] = ob; bidx[r] = oi; }
        }
        if (tm == 0) {
            int row  = q * 4 + r;
            int grow = r0 + w * 16 + row;
            widx[w * 16 + row] = bidx[r];
            out_idx[grow] = (float)bidx[r];
            idxi[grow]    = bidx[r];
        }
    }
    __syncthreads();

    float ssd = 0.f;
    for (int r = 0; r < 64; ++r) {
        int win = widx[r];
        float4 qv = ((const float4*)(cb + (long)win * ND))[tid];
        ((float4*)(out_q + (long)(r0 + r) * ND))[tid] = qv;
        float4 fv = ((const float4*)(feat + (long)(r0 + r) * ND))[tid];
        float dx = fv.x - qv.x, dy = fv.y - qv.y, dz = fv.z - qv.z, dw = fv.w - qv.w;
        ssd += dx * dx + dy * dy + dz * dz + dw * dw;
    }
    #pragma unroll
    for (int m = 1; m < 64; m <<= 1) ssd += __shfl_xor(ssd, m, 64);
    if (lane == 0) sp[w] = ssd;
    __syncthreads();
    if (tid == 0) atomicAdd(&acc[33], sp[0] + sp[1] + sp[2] + sp[3]);
}

// ---------------- fp32 tiled GEMM (only GIcb = cb @ W_ih^T) ----------------
__global__ __launch_bounds__(256) void gemm_nt(
    const float* __restrict__ A, const float* __restrict__ W,
    const float* __restrict__ bias, float* __restrict__ C, int N, int K)
{
    __shared__ float As[16][132];
    __shared__ float Bs[16][132];
    int tid = threadIdx.x;
    int m0 = blockIdx.y * 128;
    int n0 = blockIdx.x * 128;
    int tx = tid & 15, ty = tid >> 4;

    float accum[8][8];
    #pragma unroll
    for (int i = 0; i < 8; ++i)
        #pragma unroll
        for (int j = 0; j < 8; ++j) accum[i][j] = 0.f;

    for (int k0 = 0; k0 < K; k0 += 16) {
        #pragma unroll
        for (int i = 0; i < 2; ++i) {
            int f   = tid + i * 256;
            int row = f >> 2;
            int kq  = f & 3;
            float4 a = *(const float4*)(A + (long)(m0 + row) * K + k0 + kq * 4);
            As[kq * 4 + 0][row] = a.x; As[kq * 4 + 1][row] = a.y;
            As[kq * 4 + 2][row] = a.z; As[kq * 4 + 3][row] = a.w;
            float4 b = *(const float4*)(W + (long)(n0 + row) * K + k0 + kq * 4);
            Bs[kq * 4 + 0][row] = b.x; Bs[kq * 4 + 1][row] = b.y;
            Bs[kq * 4 + 2][row] = b.z; Bs[kq * 4 + 3][row] = b.w;
        }
        __syncthreads();
        #pragma unroll
        for (int kk = 0; kk < 16; ++kk) {
            float4 a01 = *(const float4*)&As[kk][ty * 8];
            float4 a23 = *(const float4*)&As[kk][ty * 8 + 4];
            float4 b01 = *(const float4*)&Bs[kk][tx * 8];
            float4 b23 = *(const float4*)&Bs[kk][tx * 8 + 4];
            float av[8] = {a01.x, a01.y, a01.z, a01.w, a23.x, a23.y, a23.z, a23.w};
            float bv[8] = {b01.x, b01.y, b01.z, b01.w, b23.x, b23.y, b23.z, b23.w};
            #pragma unroll
            for (int i = 0; i < 8; ++i)
                #pragma unroll
                for (int j = 0; j < 8; ++j) accum[i][j] += av[i] * bv[j];
        }
        __syncthreads();
    }
    #pragma unroll
    for (int i = 0; i < 8; ++i) {
        float* crow = C + (long)(m0 + ty * 8 + i) * N + n0 + tx * 8;
        const float* brow = bias + n0 + tx * 8;
        float4 o0, o1;
        o0.x = accum[i][0] + brow[0]; o0.y = accum[i][1] + brow[1];
        o0.z = accum[i][2] + brow[2]; o0.w = accum[i][3] + brow[3];
        o1.x = accum[i][4] + brow[4]; o1.y = accum[i][5] + brow[5];
        o1.z = accum[i][6] + brow[6]; o1.w = accum[i][7] + brow[7];
        *(float4*)(crow)     = o0;
        *(float4*)(crow + 4) = o1;
    }
}

// ---------------- persistent GRU v11: halved LLC read volume ----------------
// R6 diagnostic confirmed: step time tracks LLC read VOLUME of the h broadcast
// (16 MB/step = ~5 TB/s effective), not sync overhead. v11: 64 col-blocks x 16
// cols per group (128 blocks x 512 thr, 8 waves). Each wave owns a k-EIGHTH
// (4 kk), so per-wave MFMA count stays 48; per-block h read stays 64 KB but
// block count halves -> 8 MB/step total. Gate weights (g0,g1,g2) hi+lo pinned
// per-wave in registers (each wave needs only its k-eighth: 96 VGPR); W_proj
// tile in LDS (64 KB). h replicated x2 (producer stores both copies; consumer
// reads copy bidp&1) to spread the hot lines across 2x LLC channels.
// Epoch-in-data exchange (tag=step in high 16 bits of each int16-h dword).
__global__ __launch_bounds__(512, 1) void gru_persist(
    float* ctxp,
    const unsigned short* __restrict__ Whi, const unsigned short* __restrict__ Wlo,
    const unsigned short* __restrict__ Phi, const unsigned short* __restrict__ Plo,
    const float* __restrict__ GIcb, const int* __restrict__ idxi,
    const float* __restrict__ b_hh, const float* __restrict__ b_proj,
    int* hD)              // [2 buf][2 grp][2 copy][32 kk][64 lane][8] dwords
{
    __shared__ unsigned short whp[32][16][32];   // 32 KB: W_proj-hi B-frags
    __shared__ unsigned short wlp[32][16][32];   // 32 KB: W_proj-lo B-frags
    __shared__ float red[8][64][17];             // 34.8 KB: k-split partials

    int tid  = threadIdx.x;
    int lane = tid & 63;
    int w    = tid >> 6;          // 0..7 (k-eighth)
    int bid  = blockIdx.x;
    int grp  = bid >> 6;
    int bidp = bid & 63;
    int jb   = bidp * 16;
    int q    = lane >> 4;
    int tc   = lane & 15;
    int copy = bidp & 1;

    // ---- stage W_proj hi/lo into LDS (16 rows x 1024 each) ----
    for (int it = 0; it < 4; ++it) {
        int u8  = it * 512 + tid;       // 0..2047
        int row = u8 >> 7;              // 0..15
        int k   = (u8 & 127) * 8;
        int kk  = k >> 5, k32 = k & 31;
        *(s16x8*)&whp[kk][row][k32] = *(const s16x8*)(Phi + (long)(jb + row) * 1024 + k);
        *(s16x8*)&wlp[kk][row][k32] = *(const s16x8*)(Plo + (long)(jb + row) * 1024 + k);
    }

    // ---- pin gate-weight fragments in registers (wave w: k in [w*128, w*128+128)) ----
    s16x8 whf[4][3], wlf[4][3];
    #pragma unroll
    for (int kl = 0; kl < 4; ++kl) {
        int kg = w * 128 + kl * 32 + q * 8;
        #pragma unroll
        for (int g = 0; g < 3; ++g) {
            whf[kl][g] = *(const s16x8*)(Whi + (long)((g << 10) + jb + tc) * 1024 + kg);
            wlf[kl][g] = *(const s16x8*)(Wlo + (long)((g << 10) + jb + tc) * 1024 + kg);
        }
    }
    __syncthreads();

    // ---- epilogue constants (tid < 256 -> one output: batch ebg, col jg) ----
    int ebg = (tid >> 4) & 15;
    int eb  = grp * 16 + ebg;
    int ejl = tid & 15;
    int jg  = jb + ejl;
    int esidx = (ebg >> 2) * 16 + ejl;
    int eer = ebg & 3;
    float bhr = b_hh[jg], bhz = b_hh[ND + jg], bhn = b_hh[2 * ND + jg];
    float bpj = b_proj[jg];
    int akk = jg >> 5, aqp = (jg >> 3) & 3, aj8 = jg & 7;
    int alane = aqp * 16 + ebg;
    int awoff = (akk * 64 + alane) * 8 + aj8;
    float hp = 0.f;
    const float ds = 1.f / 32767.f;

    #pragma unroll 1
    for (int t = 0; t <= NT; ++t) {
        float gi0 = 0.f, gi1 = 0.f, gi2 = 0.f;
        if (tid < 256) {
            int tcl = (t < NT) ? t : (NT - 1);
            int cidx = idxi[eb * NT + tcl];
            const float* gib = GIcb + (long)cidx * NG;
            gi0 = gib[jg]; gi1 = gib[ND + jg]; gi2 = gib[2 * ND + jg];
        }

        const int* rD = hD + (((t & 1) * 2 + grp) * 2 + copy) * 16384;
        int*       wD = hD + ((((t + 1) & 1) * 2 + grp) * 2) * 16384;

        // ---- load + epoch-validate this wave's k-eighth (retry until fresh) ----
        s16x8 Ah[4], Al[4];
        if (t > 0) {
            i32x4 V[8];
            unsigned tag = ((unsigned)t) << 16;
            for (;;) {
                #pragma unroll
                for (int kl = 0; kl < 4; ++kl) {
                    const int* p = rD + (w * 4 + kl) * 512 + lane * 8;
                    V[kl * 2]     = llc_load16i(p);
                    V[kl * 2 + 1] = llc_load16i(p + 4);
                }
                asm volatile("s_waitcnt vmcnt(0)" ::: "memory");
                unsigned bad = 0;
                #pragma unroll
                for (int i = 0; i < 8; ++i) {
                    bad |= ((unsigned)V[i].x ^ tag) | ((unsigned)V[i].y ^ tag)
                         | ((unsigned)V[i].z ^ tag) | ((unsigned)V[i].w ^ tag);
                }
                if (__all((bad & 0xffff0000u) == 0)) break;
                __builtin_amdgcn_s_sleep(1);
            }
            // int16 -> exact bf16 hi/lo fragments
            #pragma unroll
            for (int kl = 0; kl < 4; ++kl) {
                s16x8 ah, al;
                #pragma unroll
                for (int pp = 0; pp < 2; ++pp) {
                    i32x4 v = V[kl * 2 + pp];
                    #pragma unroll
                    for (int e = 0; e < 4; ++e) {
                        int sv = (int)(short)(v[e] & 0xffff);
                        float f = (float)sv;
                        unsigned u = __float_as_uint(f);
                        float hif = __uint_as_float(u & 0xffff0000u);
                        float rem = f - hif;
                        ah[pp * 4 + e] = (short)(u >> 16);
                        al[pp * 4 + e] = (short)(__float_as_uint(rem) >> 16);
                    }
                }
                Ah[kl] = ah; Al[kl] = al;
            }
        } else {
            #pragma unroll
            for (int kl = 0; kl < 4; ++kl) {
                #pragma unroll
                for (int j = 0; j < 8; ++j) { Ah[kl][j] = 0; Al[kl][j] = 0; }
            }
        }

        f32x4 acc0 = (f32x4){0.f, 0.f, 0.f, 0.f};
        f32x4 acc1 = (f32x4){0.f, 0.f, 0.f, 0.f};
        f32x4 acc2 = (f32x4){0.f, 0.f, 0.f, 0.f};
        f32x4 acc3 = (f32x4){0.f, 0.f, 0.f, 0.f};

        #pragma unroll
        for (int kl = 0; kl < 4; ++kl) {
            int kk = w * 4 + kl;
            s16x8 bh3 = *(const s16x8*)&whp[kk][tc][q * 8];
            s16x8 bl3 = *(const s16x8*)&wlp[kk][tc][q * 8];
            acc0 = __builtin_amdgcn_mfma_f32_16x16x32_bf16(Ah[kl], whf[kl][0], acc0, 0, 0, 0);
            acc1 = __builtin_amdgcn_mfma_f32_16x16x32_bf16(Ah[kl], whf[kl][1], acc1, 0, 0, 0);
            acc2 = __builtin_amdgcn_mfma_f32_16x16x32_bf16(Ah[kl], whf[kl][2], acc2, 0, 0, 0);
            acc3 = __builtin_amdgcn_mfma_f32_16x16x32_bf16(Ah[kl], bh3,        acc3, 0, 0, 0);
            acc0 = __builtin_amdgcn_mfma_f32_16x16x32_bf16(Al[kl], whf[kl][0], acc0, 0, 0, 0);
            acc1 = __builtin_amdgcn_mfma_f32_16x16x32_bf16(Al[kl], whf[kl][1], acc1, 0, 0, 0);
            acc2 = __builtin_amdgcn_mfma_f32_16x16x32_bf16(Al[kl], whf[kl][2], acc2, 0, 0, 0);
            acc3 = __builtin_amdgcn_mfma_f32_16x16x32_bf16(Al[kl], bh3,        acc3, 0, 0, 0);
            acc0 = __builtin_amdgcn_mfma_f32_16x16x32_bf16(Ah[kl], wlf[kl][0], acc0, 0, 0, 0);
            acc1 = __builtin_amdgcn_mfma_f32_16x16x32_bf16(Ah[kl], wlf[kl][1], acc1, 0, 0, 0);
            acc2 = __builtin_amdgcn_mfma_f32_16x16x32_bf16(Ah[kl], wlf[kl][2], acc2, 0, 0, 0);
            acc3 = __builtin_amdgcn_mfma_f32_16x16x32_bf16(Ah[kl], bl3,        acc3, 0, 0, 0);
        }

        #pragma unroll
        for (int r = 0; r < 4; ++r) {
            red[w][lane][r]      = acc0[r];
            red[w][lane][4 + r]  = acc1[r];
            red[w][lane][8 + r]  = acc2[r];
            red[w][lane][12 + r] = acc3[r];
        }
        __syncthreads();

        if (tid < 256) {
            float g0 = 0.f, g1 = 0.f, g2 = 0.f, cx = 0.f;
            #pragma unroll
            for (int ww = 0; ww < 8; ++ww) {
                g0 += red[ww][esidx][eer];
                g1 += red[ww][esidx][4 + eer];
                g2 += red[ww][esidx][8 + eer];
                cx += red[ww][esidx][12 + eer];
            }
            if (t < NT) {
                float xr = gi0 + g0 * ds + bhr;
                float xz = gi1 + g1 * ds + bhz;
                float rg = 1.f / (1.f + __expf(-xr));
                float zg = 1.f / (1.f + __expf(-xz));
                float narg = gi2 + rg * (g2 * ds + bhn);
                float e2 = __expf(2.f * narg);
                float ng = 1.f - 2.f / (e2 + 1.f);
                float hnew = (1.f - zg) * ng + zg * hp;
                hp = hnew;
                int hv = (int)rintf(hnew * 32767.f);
                unsigned word = ((unsigned)hv & 0xffffu)
                              | (((unsigned)(t + 1) & 0xffffu) << 16);
                llc_store4(wD + awoff, (int)word);            // copy 0
                llc_store4(wD + 16384 + awoff, (int)word);    // copy 1
            }
            if (t > 0) {
                // ctx row t-1 (A-frags this step were h(t-1)); no consumer until cp.
                ctxp[((long)eb * NT + (t - 1)) * ND + jg] = cx * ds + bpj;
            }
        }
        __syncthreads();   // red[] reuse guard
    }
}

// ---------------- fused CPC loss: blocks 0..510 = S-matrix negs, 511.. = pos ----------------
__global__ __launch_bounds__(256) void cp_fused(
    const float* __restrict__ feat, const float* __restrict__ ctx,
    const int* __restrict__ perm, float* __restrict__ acc)
{
    __shared__ float S[32][33];
    __shared__ float red2[4];

    int bid = blockIdx.x;
    int t = threadIdx.x;

    if (bid < 511) {
        int l = bid;
        int b = t >> 3;
        int n0 = (t & 7) * 4;

        const float4* crow = (const float4*)(ctx + ((long)b * NT + l) * ND);
        const float4* f0 = (const float4*)(feat + ((long)(n0 + 0) * NT + l) * ND);
        const float4* f1 = (const float4*)(feat + ((long)(n0 + 1) * NT + l) * ND);
        const float4* f2 = (const float4*)(feat + ((long)(n0 + 2) * NT + l) * ND);
        const float4* f3 = (const float4*)(feat + ((long)(n0 + 3) * NT + l) * ND);
        float s0 = 0.f, s1 = 0.f, s2 = 0.f, s3 = 0.f;
        for (int j = 0; j < 256; ++j) {
            float4 cv = crow[j];
            float4 v0 = f0[j]; s0 += cv.x * v0.x + cv.y * v0.y + cv.z * v0.z + cv.w * v0.w;
            float4 v1 = f1[j]; s1 += cv.x * v1.x + cv.y * v1.y + cv.z * v1.z + cv.w * v1.w;
            float4 v2 = f2[j]; s2 += cv.x * v2.x + cv.y * v2.y + cv.z * v2.z + cv.w * v2.w;
            float4 v3 = f3[j]; s3 += cv.x * v3.x + cv.y * v3.y + cv.z * v3.z + cv.w * v3.w;
        }
        S[b][n0] = s0; S[b][n0 + 1] = s1; S[b][n0 + 2] = s2; S[b][n0 + 3] = s3;
        __syncthreads();

        float nsum = 0.f;
        #pragma unroll
        for (int k = 0; k < 3; ++k) {
            if (l < 511 - k) {
                #pragma unroll
                for (int i = 0; i < 4; ++i) {
                    int idx = t + i * 256;
                    int b2 = idx >> 5, n = idx & 31;
                    int p = perm[k * 32 + n];
                    float x = S[b2][p];
                    float sn = 1.f / (1.f + expf(x));
                    nsum += -logf(sn + 1e-8f);
                }
            }
        }
        #pragma unroll
        for (int m = 1; m < 64; m <<= 1) nsum += __shfl_xor(nsum, m, 64);
        if ((t & 63) == 0) red2[t >> 6] = nsum;
        __syncthreads();
        if (t == 0) atomicAdd(&acc[32], red2[0] + red2[1] + red2[2] + red2[3]);
    } else {
        int r = bid - 511;
        int b    = r >> 2;
        int q4   = r & 3;
        int wv   = t >> 6;
        int lane = t & 63;
        int l0   = q4 * 128 + wv * 32;
        const float* cb_ = ctx + (long)b * NT * ND;
        const float* fb_ = feat + (long)b * NT * ND;

        float F1[16], F2[16], F3[16];
        #pragma unroll
        for (int j = 0; j < 16; ++j) {
            F1[j] = fb_[(long)(l0 + 1) * ND + j * 64 + lane];
            F2[j] = fb_[(long)(l0 + 2) * ND + j * 64 + lane];
            F3[j] = fb_[(long)(l0 + 3) * ND + j * 64 + lane];
        }
        float posacc = 0.f;
        for (int li = 0; li < 32; ++li) {
            int l = l0 + li;
            float p1 = 0.f, p2 = 0.f, p3 = 0.f;
            #pragma unroll
            for (int j = 0; j < 16; ++j) {
                float cv = cb_[(long)l * ND + j * 64 + lane];
                p1 += cv * F1[j]; p2 += cv * F2[j]; p3 += cv * F3[j];
            }
            #pragma unroll
            for (int m = 1; m < 64; m <<= 1) {
                p1 += __shfl_xor(p1, m, 64);
                p2 += __shfl_xor(p2, m, 64);
                p3 += __shfl_xor(p3, m, 64);
            }
            if (l + 1 < NT) posacc += -logf(1.f / (1.f + expf(-p1)) + 1e-8f);
            if (l + 2 < NT) posacc += -logf(1.f / (1.f + expf(-p2)) + 1e-8f);
            if (l + 3 < NT) posacc += -logf(1.f / (1.f + expf(-p3)) + 1e-8f);
            #pragma unroll
            for (int j = 0; j < 16; ++j) { F1[j] = F2[j]; F2[j] = F3[j]; }
            if (l + 4 < NT) {
                #pragma unroll
                for (int j = 0; j < 16; ++j) F3[j] = fb_[(long)(l + 4) * ND + j * 64 + lane];
            }
        }
        if (lane == 0) atomicAdd(&acc[b], posacc);
    }
}

// ---------------- finalize ----------------
__global__ void finalize_kernel(const float* __restrict__ acc, float* __restrict__ out) {
    int b = threadIdx.x;
    if (b < 32) {
        float cp = (acc[b] + 0.25f * acc[32] * (1.0f / 1024.0f)) * (1.0f / 1527.0f);
        float vq = 1.25f * acc[33] * (1.0f / 16777216.0f);
        out[b] = cp + vq;
    }
}

// ---------------- launch ----------------
extern "C" void kernel_launch(void* const* d_in, const int* in_sizes, int n_in,
                              void* d_out, int out_size, void* d_ws, size_t ws_size,
                              hipStream_t stream)
{
    const float* feat   = (const float*)d_in[0];
    const float* cb     = (const float*)d_in[1];
    const float* W_ih   = (const float*)d_in[2];
    const float* W_hh   = (const float*)d_in[3];
    const float* b_ih   = (const float*)d_in[4];
    const float* b_hh   = (const float*)d_in[5];
    const float* W_proj = (const float*)d_in[6];
    const float* b_proj = (const float*)d_in[7];
    const int*   nperm  = (const int*)d_in[8];

    float* outq    = (float*)d_out;
    float* outidx  = outq + 16777216;
    float* outloss = outq + 16793600;

    char* ws = (char*)d_ws;
    float*          ctx  = (float*)(ws);                       //  67,108,864 B
    unsigned short* Whi  = (unsigned short*)(ws + 67108864);   //   6,291,456 B
    unsigned short* Wlo  = (unsigned short*)(ws + 73400320);   //   6,291,456 B
    unsigned short* Phi  = (unsigned short*)(ws + 79691776);   //   2,097,152 B
    unsigned short* Plo  = (unsigned short*)(ws + 81788928);   //   2,097,152 B
    float*          GIcb = (float*)(ws + 83886080);            //   3,145,728 B
    int*            idxi = (int*)(ws + 87031808);              //      65,536 B
    float*          acc  = (float*)(ws + 87097344);            //  256 B
    int*            hD   = (int*)(ws + 87097600);              //  524,288 B h dword bufs (2 buf x 2 grp x 2 copy)
    unsigned short* cbHi = (unsigned short*)(ws + 87621888);   //  524,288 B
    unsigned short* cbLo = (unsigned short*)(ws + 88146176);   //  524,288 B
    float*          ccg  = (float*)(ws + 88670464);            //    1,024 B

    // zero acc (256) + hD all buffers (524288): epochs must start != any step tag
    hipMemsetAsync(acc, 0, 256 + 524288, stream);
    // fused prep: W_hh/W_proj/cb hi-lo splits + ||c||^2   (2177 blocks)
    prep_fused<<<2177, 256, 0, stream>>>(W_hh, W_proj, cb, Whi, Wlo, Phi, Plo,
                                         cbHi, cbLo, ccg);
    quantize_mfma<<<256, 256, 0, stream>>>(feat, cb, cbHi, cbLo, ccg,
                                           outq, outidx, idxi, acc);
    // GIcb = codebook @ W_ih^T + b_ih  (256x3072, K=1024)
    gemm_nt<<<dim3(24, 2), 256, 0, stream>>>(cb, W_ih, b_ih, GIcb, NG, ND);
    // persistent GRU: 513 in-kernel steps, ctx fused, epoch-in-data, 16-col blocks
    gru_persist<<<GRU_BLOCKS, 512, 0, stream>>>(ctx, Whi, Wlo, Phi, Plo, GIcb, idxi,
                                                b_hh, b_proj, hD);
    // fused CPC loss: 511 S-blocks + 128 pos-blocks
    cp_fused<<<639, 256, 0, stream>>>(feat, ctx, nperm, acc);
    finalize_kernel<<<1, 64, 0, stream>>>(acc, outloss);
}